// Round 3
// baseline (1970.429 us; speedup 1.0000x reference)
//
#include <hip/hip_runtime.h>

typedef __bf16 v8bf __attribute__((ext_vector_type(8)));
typedef float v4f __attribute__((ext_vector_type(4)));
typedef float v4ff __attribute__((ext_vector_type(4)));
typedef unsigned short u16;
typedef unsigned int u32;

#define DEVI __device__ __forceinline__

constexpr int LX = 168, FF = 64;
constexpr int LY = 72, FT = 22, FOUTC = 10;
constexpr int HID = 256;
constexpr int HSTR = 264;   // u16/row for 16x256 tiles (528B = 33*16)
constexpr int UST2 = 40;
constexpr int SSTR = 264;   // slab row stride

// bf16 weight cache layout in d_ws (u16 element offsets; all 16B-aligned)
constexpr int W_EWIH = 0;                      // 768*64
constexpr int W_EWHH = 49152;                  // 768*256
constexpr int W_DWIH = 245760;                 // 768*32
constexpr int W_DWHH = 270336;                 // 768*256
constexpr int W_THW0 = 466944;                 // 128*256
constexpr int W_THW1 = 499712;                 // 2*128
constexpr int W_CLW0 = 499968;                 // 128*256
constexpr int W_CLW1 = 532736;                 // 8*128
constexpr int W_TOTAL = 533760;

DEVI u16 f2bf(float f) {
  u32 x; __builtin_memcpy(&x, &f, 4);
  return (u16)((x + 0x7FFFu + ((x >> 16) & 1u)) >> 16);  // RNE (h feeds recurrence)
}
DEVI float sigm(float x) { return __builtin_amdgcn_rcpf(1.f + __expf(-x)); }
DEVI float tanh_(float x) {
  float e = __expf(-2.f * fabsf(x));
  return copysignf((1.f - e) * __builtin_amdgcn_rcpf(1.f + e), x);
}
DEVI float smelu_(float x) {
  if (x >= 1.1f) return x;
  if (x <= -1.1f) return 0.f;
  float u = x + 1.1f;
  return u * u * (1.f / 4.4f);
}
DEVI v8bf ld8(const u16* p) { return *reinterpret_cast<const v8bf*>(p); }
DEVI v4f ldw(const u16* p) { return *reinterpret_cast<const v4f*>(p); }
DEVI v8bf asbf(v4f x) { return __builtin_bit_cast(v8bf, x); }
DEVI void pin(v4f& x) { asm("" : "+v"(x)); }       // defeat rematerialization
DEVI v4f mfma16(v8bf a, v8bf b, v4f c) {
  return __builtin_amdgcn_mfma_f32_16x16x32_bf16(a, b, c, 0, 0, 0);
}
DEVI v8bf cvt2f(v4ff lo, v4ff hi) {
  v8bf r;
#pragma unroll
  for (int j = 0; j < 4; ++j) { r[j] = (__bf16)lo[j]; r[4 + j] = (__bf16)hi[j]; }
  return r;
}

// ---- prologue: convert all weight matrices f32 -> bf16 into d_ws ----
__global__ void cvt_weights(const float* __restrict__ eWih, const float* __restrict__ eWhh,
                            const float* __restrict__ dWih, const float* __restrict__ dWhh,
                            const float* __restrict__ thW0, const float* __restrict__ thW1,
                            const float* __restrict__ clW0, const float* __restrict__ clW1,
                            u16* __restrict__ ws) {
  const int i = blockIdx.x * 256 + threadIdx.x;
  if (i >= W_TOTAL) return;
  const float* src; int off;
  if      (i < W_EWHH) { src = eWih; off = W_EWIH; }
  else if (i < W_DWIH) { src = eWhh; off = W_EWHH; }
  else if (i < W_DWHH) { src = dWih; off = W_DWIH; }
  else if (i < W_THW0) { src = dWhh; off = W_DWHH; }
  else if (i < W_THW1) { src = thW0; off = W_THW0; }
  else if (i < W_CLW0) { src = thW1; off = W_THW1; }
  else if (i < W_CLW1) { src = clW0; off = W_CLW0; }
  else                 { src = clW1; off = W_CLW1; }
  ws[i] = f2bf(src[i - off]);
}

// 256 threads = 4 waves at 1 wave/SIMD (512 unified regs/wave).
// Wave w owns col-tiles c = 4w..4w+3. Parked in regs: z,n Whh for all 4
// tiles (256 regs) + r Whh for tiles j=0,1 (64 regs) = 320 pinned.
// Slab holds only the 8 non-parked r tiles (c in {2,3,6,7,10,11,14,15}),
// halving per-step LDS reads vs the 132KB full slab. Working-set audit:
// pinned 320 + a[8] 32 + accums 48..64 + hreg 16 + bias 16 + xa 8 + misc
// ~20 = ~470 < 512 (rounds 1-2 died on exactly this arithmetic).
// Encoder: h dbuf, 1 barrier/step. Decoder: h dbuf + a1 dbuf -> 1
// barrier/step (round 0 had 2); gemm2 rotates across waves (t&3) to
// remove the wave-0 straggler.
__global__ __launch_bounds__(256, 1) void encdec_kernel(
    const float* __restrict__ xf, const float* __restrict__ yt, const float* __restrict__ pp,
    const float* __restrict__ ebih, const float* __restrict__ ebhh,
    const float* __restrict__ dbih, const float* __restrict__ dbhh,
    const float* __restrict__ thb0, const float* __restrict__ thb1,
    const float* __restrict__ clb0, const float* __restrict__ clb1,
    const u16* __restrict__ ws, float* __restrict__ outp) {
  __shared__ __align__(16) u16 slab[128 * SSTR];   // r-gate Whh, 8 tiles (67.6 KB)
  __shared__ __align__(16) u16 hls[2][16 * HSTR];  // h double buffer
  __shared__ __align__(16) u16 a1d[2][16 * HSTR];  // a1 double buffer
  __shared__ __align__(16) u16 uls[2][16 * UST2];

  const u16* eWih = ws + W_EWIH;
  const u16* eWhh = ws + W_EWHH;
  const u16* dWih = ws + W_DWIH;
  const u16* dWhh = ws + W_DWHH;
  const u16* thW0 = ws + W_THW0;
  const u16* thW1 = ws + W_THW1;
  const u16* clW0 = ws + W_CLW0;
  const u16* clW1 = ws + W_CLW1;

  const int tid = threadIdx.x;
  const int wave = tid >> 6;        // 4 waves
  const int lane = tid & 63;
  const int col16 = lane & 15;
  const int quad = lane >> 4;
  const int n0 = blockIdx.x * 16;

  float hreg[4][4];
#pragma unroll
  for (int j = 0; j < 4; ++j)
#pragma unroll
    for (int r = 0; r < 4; ++r) hreg[j][r] = 0.f;

  // Persistent weight fragments (320 regs total; VGPR+AGPR unified file).
  v4f wz[4][8], wn[4][8], wr[2][8];
  float bsr[4], bsz[4], bin_[4], bhn[4];

  // slab compact mapping: slab tile ct (0..7) <-> col-tile c = (ct>>1)*4 + 2 + (ct&1)
  const u16* sp2 = slab + ((wave * 2 + 0) * 16 + col16) * SSTR + quad * 8;
  const u16* sp3 = slab + ((wave * 2 + 1) * 16 + col16) * SSTR + quad * 8;

  // ================= encoder phase =================
  {
    for (int i = tid; i < 128 * 32; i += 256) {   // stage compact r slab
      const int sr = i >> 5, kb = (i & 31) << 3;
      const int ct = sr >> 4;
      const int c = (ct >> 1) * 4 + 2 + (ct & 1);
      const int m = c * 16 + (sr & 15);
      *reinterpret_cast<v8bf*>(&slab[sr * SSTR + kb]) = ld8(eWhh + (size_t)m * HID + kb);
    }
    for (int i = tid; i < 16 * HSTR; i += 256) hls[0][i] = 0;
#pragma unroll
    for (int j = 0; j < 4; ++j) {
      const int c = wave * 4 + j;
      const int mr = c * 16 + col16, mz = 256 + mr, mn = 512 + mr;
#pragma unroll
      for (int k = 0; k < 8; ++k) {
        wz[j][k] = ldw(eWhh + (size_t)mz * HID + k * 32 + quad * 8); pin(wz[j][k]);
        wn[j][k] = ldw(eWhh + (size_t)mn * HID + k * 32 + quad * 8); pin(wn[j][k]);
      }
      bsr[j] = ebih[mr] + ebhh[mr];
      bsz[j] = ebih[mz] + ebhh[mz];
      bin_[j] = ebih[mn];
      bhn[j] = ebhh[mn];
    }
#pragma unroll
    for (int j = 0; j < 2; ++j) {
      const int mr = (wave * 4 + j) * 16 + col16;
#pragma unroll
      for (int k = 0; k < 8; ++k) {
        wr[j][k] = ldw(eWhh + (size_t)mr * HID + k * 32 + quad * 8); pin(wr[j][k]);
      }
    }
    const float* xbase = xf + (size_t)(n0 + col16) * LX * FF + quad * 8;

    // x(0) fragments pre-cvt'd
    v8bf xa0, xa1;
    {
      const v4ff x0 = *(const v4ff*)(xbase);
      const v4ff x1 = *(const v4ff*)(xbase + 4);
      const v4ff x2 = *(const v4ff*)(xbase + 32);
      const v4ff x3 = *(const v4ff*)(xbase + 36);
      xa0 = cvt2f(x0, x1);
      xa1 = cvt2f(x2, x3);
    }
    __syncthreads();  // slab + h-init visible

#pragma unroll 1
    for (int t = 0; t < LX; ++t) {
      const u16* hb = hls[t & 1] + col16 * HSTR + quad * 8;
      v8bf a[8];
#pragma unroll
      for (int k = 0; k < 8; ++k) a[k] = ld8(hb + k * 32);

      v4f az[4], ar[4], an[4];
#pragma unroll
      for (int j = 0; j < 4; ++j) {
        az[j] = (v4f){bsz[j], bsz[j], bsz[j], bsz[j]};
        ar[j] = (v4f){bsr[j], bsr[j], bsr[j], bsr[j]};
        an[j] = (v4f){bhn[j], bhn[j], bhn[j], bhn[j]};
      }
      // 12 independent h-chains (r tiles 2,3 stream from slab)
#pragma unroll
      for (int k = 0; k < 8; ++k) {
        az[0] = mfma16(a[k], asbf(wz[0][k]), az[0]);
        az[1] = mfma16(a[k], asbf(wz[1][k]), az[1]);
        az[2] = mfma16(a[k], asbf(wz[2][k]), az[2]);
        az[3] = mfma16(a[k], asbf(wz[3][k]), az[3]);
        ar[0] = mfma16(a[k], asbf(wr[0][k]), ar[0]);
        ar[1] = mfma16(a[k], asbf(wr[1][k]), ar[1]);
        ar[2] = mfma16(a[k], ld8(sp2 + k * 32), ar[2]);
        ar[3] = mfma16(a[k], ld8(sp3 + k * 32), ar[3]);
        an[0] = mfma16(a[k], asbf(wn[0][k]), an[0]);
        an[1] = mfma16(a[k], asbf(wn[1][k]), an[1]);
        an[2] = mfma16(a[k], asbf(wn[2][k]), an[2]);
        an[3] = mfma16(a[k], asbf(wn[3][k]), an[3]);
      }
      // x-part (uses xa pre-cvt'd last step)
      v4f ai[4];
#pragma unroll
      for (int j = 0; j < 4; ++j) {
        const int m = (wave * 4 + j) * 16 + col16;
        const u16* pwr = eWih + (size_t)m * FF + quad * 8;
        const u16* pwz = eWih + (size_t)(256 + m) * FF + quad * 8;
        const u16* pwn = eWih + (size_t)(512 + m) * FF + quad * 8;
        ai[j] = (v4f){bin_[j], bin_[j], bin_[j], bin_[j]};
        az[j] = mfma16(xa0, ld8(pwz), az[j]);
        az[j] = mfma16(xa1, ld8(pwz + 32), az[j]);
        ar[j] = mfma16(xa0, ld8(pwr), ar[j]);
        ar[j] = mfma16(xa1, ld8(pwr + 32), ar[j]);
        ai[j] = mfma16(xa0, ld8(pwn), ai[j]);
        ai[j] = mfma16(xa1, ld8(pwn + 32), ai[j]);
      }
      // issue x(t+1) loads (consumed by cvt after the pointwise)
      const int tn = (t + 1 < LX) ? t + 1 : t;
      const float* xr = xbase + (size_t)tn * FF;
      const v4ff x0 = *(const v4ff*)(xr);
      const v4ff x1 = *(const v4ff*)(xr + 4);
      const v4ff x2 = *(const v4ff*)(xr + 32);
      const v4ff x3 = *(const v4ff*)(xr + 36);

#pragma unroll
      for (int j = 0; j < 4; ++j) {
        const int cx = (wave * 4 + j) * 16 + col16;
#pragma unroll
        for (int r = 0; r < 4; ++r) {
          const float zg = sigm(az[j][r]);
          const float rg = sigm(ar[j][r]);
          const float ng = tanh_(ai[j][r] + rg * an[j][r]);
          hreg[j][r] = (1.f - zg) * ng + zg * hreg[j][r];
          hls[(t + 1) & 1][(quad * 4 + r) * HSTR + cx] = f2bf(hreg[j][r]);
        }
      }
      xa0 = cvt2f(x0, x1);
      xa1 = cvt2f(x2, x3);
      __syncthreads();
    }
  }
  // h_enc in hls[LX & 1] == hls[0]  (LX even)

  // ================= decoder phase =================
  {
    for (int i = tid; i < 128 * 32; i += 256) {   // restage slab from dWhh
      const int sr = i >> 5, kb = (i & 31) << 3;
      const int ct = sr >> 4;
      const int c = (ct >> 1) * 4 + 2 + (ct & 1);
      const int m = c * 16 + (sr & 15);
      *reinterpret_cast<v8bf*>(&slab[sr * SSTR + kb]) = ld8(dWhh + (size_t)m * HID + kb);
    }
#pragma unroll
    for (int j = 0; j < 4; ++j) {
      const int c = wave * 4 + j;
      const int mr = c * 16 + col16, mz = 256 + mr, mn = 512 + mr;
#pragma unroll
      for (int k = 0; k < 8; ++k) {
        wz[j][k] = ldw(dWhh + (size_t)mz * HID + k * 32 + quad * 8); pin(wz[j][k]);
        wn[j][k] = ldw(dWhh + (size_t)mn * HID + k * 32 + quad * 8); pin(wn[j][k]);
      }
      bsr[j] = dbih[mr] + dbhh[mr];
      bsz[j] = dbih[mz] + dbhh[mz];
      bin_[j] = dbih[mn];
      bhn[j] = dbhh[mn];
    }
#pragma unroll
    for (int j = 0; j < 2; ++j) {
      const int mr = (wave * 4 + j) * 16 + col16;
#pragma unroll
      for (int k = 0; k < 8; ++k) {
        wr[j][k] = ldw(dWhh + (size_t)mr * HID + k * 32 + quad * 8); pin(wr[j][k]);
      }
    }
    // head tile assignment: ht = wave*4 + j; ht<8 -> temphr, else class
    const u16* pW0[4]; float hb0[4];
#pragma unroll
    for (int j = 0; j < 4; ++j) {
      const int h = wave * 4 + j;
      const int row = (h & 7) * 16 + col16;
      pW0[j] = ((h < 8) ? thW0 : clW0) + (size_t)row * HID + quad * 8;
      hb0[j] = (h < 8) ? thb0[row] : clb0[row];
    }
    const bool w1th = (col16 < 2);
    const bool w1cl = (col16 >= 2 && col16 < FOUTC);
    const float b1v = w1th ? thb1[col16] : (w1cl ? clb1[col16 - 2] : 0.f);

    const int scc = tid & 31;
    const int srr = tid >> 5;            // 0..7; each thread stages rows srr, srr+8
    {  // stage u_0 (src_t = 0)
#pragma unroll
      for (int rr = srr; rr < 16; rr += 8) {
        const size_t yb = (size_t)(n0 + rr) * (LY + 1);
        const float v = (scc < FT) ? yt[yb * FT + scc] : pp[yb * FOUTC + (scc - FT)];
        uls[0][rr * UST2 + scc] = f2bf(v);
      }
    }

    // GEMM2 for step s reads a1d[s & 1]; writes outp row s.
    auto gemm2 = [&](int s) {
      const u16* arow = a1d[s & 1] + col16 * HSTR + quad * 8;
      v4f acc = {b1v, b1v, b1v, b1v};
#pragma unroll
      for (int kt = 0; kt < 8; ++kt) {
        v8bf b;
#pragma unroll
        for (int j = 0; j < 8; ++j) b[j] = (__bf16)0.0f;
        if (kt < 4) { if (w1th) b = ld8(thW1 + col16 * 128 + kt * 32 + quad * 8); }
        else        { if (w1cl) b = ld8(clW1 + (col16 - 2) * 128 + (kt - 4) * 32 + quad * 8); }
        acc = mfma16(ld8(arow + kt * 32), b, acc);
      }
      if (col16 < FOUTC) {
#pragma unroll
        for (int r = 0; r < 4; ++r)
          outp[((size_t)(n0 + quad * 4 + r) * LY + s) * FOUTC + col16] = acc[r];
      }
    };

    // GEMM1: a1(s) = smelu(H(s+1) @ W0^T + b0); A from hbase; writes a1d[s & 1].
    auto gemm1 = [&](const u16* hbase, u16* a1w) {
      const u16* hA = hbase + col16 * HSTR + quad * 8;
      v4f acc[4];
#pragma unroll
      for (int j = 0; j < 4; ++j) acc[j] = (v4f){hb0[j], hb0[j], hb0[j], hb0[j]};
#pragma unroll
      for (int k = 0; k < 8; ++k) {
        const v8bf hk = ld8(hA + k * 32);
        acc[0] = mfma16(hk, ld8(pW0[0] + k * 32), acc[0]);
        acc[1] = mfma16(hk, ld8(pW0[1] + k * 32), acc[1]);
        acc[2] = mfma16(hk, ld8(pW0[2] + k * 32), acc[2]);
        acc[3] = mfma16(hk, ld8(pW0[3] + k * 32), acc[3]);
      }
#pragma unroll
      for (int j = 0; j < 4; ++j) {
        const int hcol = (wave * 4 + j) * 16 + col16;
#pragma unroll
        for (int r = 0; r < 4; ++r)
          a1w[(quad * 4 + r) * HSTR + hcol] = f2bf(smelu_(acc[j][r]));
      }
    };

    __syncthreads();  // slab + u_0 visible

    // One barrier/step. Buffer plan at step t:
    //   gates read hls[t&1], write hls[(t+1)&1]
    //   gemm1(t-1) reads hls[t&1], writes a1d[(t-1)&1] (= a1d[(t+1)&1])
    //   gemm2(t-2) reads a1d[t&1]  (written at step t-1)  -> disjoint, no race
#pragma unroll 1
    for (int t = 0; t < LY; ++t) {
      float un0 = 0.f, un1 = 0.f;
      if (t + 1 < LY) {
        const size_t yb0 = (size_t)(n0 + srr) * (LY + 1) + t;
        const size_t yb1 = (size_t)(n0 + srr + 8) * (LY + 1) + t;
        un0 = (scc < FT) ? yt[yb0 * FT + scc] : pp[yb0 * FOUTC + (scc - FT)];
        un1 = (scc < FT) ? yt[yb1 * FT + scc] : pp[yb1 * FOUTC + (scc - FT)];
      }

      if (wave == (t & 3) && t >= 2) gemm2(t - 2);   // rotate the extra job

      const v8bf ua = ld8(uls[t & 1] + col16 * UST2 + quad * 8);
      const u16* hb = hls[t & 1] + col16 * HSTR + quad * 8;

      v4f az[4], ar[4], an[4];
#pragma unroll
      for (int j = 0; j < 4; ++j) {
        az[j] = (v4f){bsz[j], bsz[j], bsz[j], bsz[j]};
        ar[j] = (v4f){bsr[j], bsr[j], bsr[j], bsr[j]};
        an[j] = (v4f){bhn[j], bhn[j], bhn[j], bhn[j]};
      }
#pragma unroll
      for (int k = 0; k < 8; ++k) {
        const v8bf ak = ld8(hb + k * 32);      // h read on the fly (dbuf'd)
        az[0] = mfma16(ak, asbf(wz[0][k]), az[0]);
        az[1] = mfma16(ak, asbf(wz[1][k]), az[1]);
        az[2] = mfma16(ak, asbf(wz[2][k]), az[2]);
        az[3] = mfma16(ak, asbf(wz[3][k]), az[3]);
        ar[0] = mfma16(ak, asbf(wr[0][k]), ar[0]);
        ar[1] = mfma16(ak, asbf(wr[1][k]), ar[1]);
        ar[2] = mfma16(ak, ld8(sp2 + k * 32), ar[2]);
        ar[3] = mfma16(ak, ld8(sp3 + k * 32), ar[3]);
        an[0] = mfma16(ak, asbf(wn[0][k]), an[0]);
        an[1] = mfma16(ak, asbf(wn[1][k]), an[1]);
        an[2] = mfma16(ak, asbf(wn[2][k]), an[2]);
        an[3] = mfma16(ak, asbf(wn[3][k]), an[3]);
      }
      v4f ai[4];
#pragma unroll
      for (int j = 0; j < 4; ++j) {
        const int m = (wave * 4 + j) * 16 + col16;
        ai[j] = (v4f){bin_[j], bin_[j], bin_[j], bin_[j]};
        az[j] = mfma16(ua, ld8(dWih + (size_t)(256 + m) * 32 + quad * 8), az[j]);
        ar[j] = mfma16(ua, ld8(dWih + (size_t)m * 32 + quad * 8), ar[j]);
        ai[j] = mfma16(ua, ld8(dWih + (size_t)(512 + m) * 32 + quad * 8), ai[j]);
      }
#pragma unroll
      for (int j = 0; j < 4; ++j) {
        const int cx = (wave * 4 + j) * 16 + col16;
#pragma unroll
        for (int r = 0; r < 4; ++r) {
          const float zg = sigm(az[j][r]);
          const float rg = sigm(ar[j][r]);
          const float ng = tanh_(ai[j][r] + rg * an[j][r]);
          hreg[j][r] = (1.f - zg) * ng + zg * hreg[j][r];
          hls[(t + 1) & 1][(quad * 4 + r) * HSTR + cx] = f2bf(hreg[j][r]);
        }
      }

      if (t >= 1) gemm1(hls[t & 1], a1d[(t - 1) & 1]);   // a1(t-1) from h_t

      if (t + 1 < LY) {
        uls[(t + 1) & 1][srr * UST2 + scc] = f2bf(un0);
        uls[(t + 1) & 1][(srr + 8) * UST2 + scc] = f2bf(un1);
      }
      __syncthreads();  // h(t+1), u(t+1), a1(t-1) visible; a1/gemm2 reads done
    }

    // ---- epilogue ----
    // a1(LY-2) is in a1d[(LY-2)&1] = a1d[0] (fenced by final loop barrier).
    gemm1(hls[LY & 1], a1d[(LY - 1) & 1]);   // a1(LY-1) from h_LY; writes a1d[1]
    if (wave == 0) gemm2(LY - 2);            // reads a1d[0], no conflict
    __syncthreads();
    if (wave == 0) gemm2(LY - 1);            // reads a1d[1]
  }
}

extern "C" void kernel_launch(void* const* d_in, const int* in_sizes, int n_in,
                              void* d_out, int out_size, void* d_ws, size_t ws_size,
                              hipStream_t stream) {
  (void)in_sizes; (void)n_in; (void)ws_size; (void)out_size;
  const float* xf   = (const float*)d_in[0];
  // d_in[1] = x : unused by forward
  const float* yt   = (const float*)d_in[2];
  const float* pp   = (const float*)d_in[3];
  const float* eWih = (const float*)d_in[4];
  const float* eWhh = (const float*)d_in[5];
  const float* ebih = (const float*)d_in[6];
  const float* ebhh = (const float*)d_in[7];
  const float* dWih = (const float*)d_in[8];
  const float* dWhh = (const float*)d_in[9];
  const float* dbih = (const float*)d_in[10];
  const float* dbhh = (const float*)d_in[11];
  const float* thW0 = (const float*)d_in[12];
  const float* thb0 = (const float*)d_in[13];
  const float* thW1 = (const float*)d_in[14];
  const float* thb1 = (const float*)d_in[15];
  const float* clW0 = (const float*)d_in[16];
  const float* clb0 = (const float*)d_in[17];
  const float* clW1 = (const float*)d_in[18];
  const float* clb1 = (const float*)d_in[19];
  float* outp = (float*)d_out;
  u16* ws = (u16*)d_ws;  // needs W_TOTAL*2 ~= 1.04 MB of scratch

  cvt_weights<<<dim3((W_TOTAL + 255) / 256), dim3(256), 0, stream>>>(
      eWih, eWhh, dWih, dWhh, thW0, thW1, clW0, clW1, ws);
  encdec_kernel<<<dim3(128), dim3(256), 0, stream>>>(
      xf, yt, pp, ebih, ebhh, dbih, dbhh, thb0, thb1, clb0, clb1, ws, outp);
}

// Round 4
// 1216.863 us; speedup vs baseline: 1.6193x; 1.6193x over previous
//
#include <hip/hip_runtime.h>

typedef __bf16 v8bf __attribute__((ext_vector_type(8)));
typedef float v4f __attribute__((ext_vector_type(4)));
typedef unsigned short u16;
typedef unsigned int u32;

#define DEVI __device__ __forceinline__

constexpr int LX = 168, FF = 64;
constexpr int LY = 72, FT = 22, FOUTC = 10;
constexpr int HID = 256;
constexpr int HSTR = 264;   // u16/row for 16x256 tiles (528B = 33*16)
constexpr int UST2 = 40;
constexpr int SSTR = 264;   // slab row stride
constexpr int XSTR = 72;    // encoder x-stage row stride (u16)

// bf16 weight cache layout in d_ws (u16 element offsets; all 16B-aligned)
constexpr int W_EWIH = 0;                      // 768*64
constexpr int W_EWHH = 49152;                  // 768*256
constexpr int W_DWIH = 245760;                 // 768*32
constexpr int W_DWHH = 270336;                 // 768*256
constexpr int W_THW0 = 466944;                 // 128*256
constexpr int W_THW1 = 499712;                 // 2*128
constexpr int W_CLW0 = 499968;                 // 128*256
constexpr int W_CLW1 = 532736;                 // 8*128
constexpr int W_W1F  = 533760;                 // fused padded W1: 16 x 256
constexpr int W_TOTAL  = 533760;
constexpr int W_TOTALF = 537856;               // incl. W1F

DEVI u16 f2bf(float f) {
  u32 x; __builtin_memcpy(&x, &f, 4);
  return (u16)((x + 0x7FFFu + ((x >> 16) & 1u)) >> 16);  // RNE (h feeds recurrence)
}
DEVI float sigm(float x) { return __builtin_amdgcn_rcpf(1.f + __expf(-x)); }
DEVI float tanh_(float x) {
  float e = __expf(-2.f * fabsf(x));
  return copysignf((1.f - e) * __builtin_amdgcn_rcpf(1.f + e), x);
}
DEVI float smelu_(float x) {
  if (x >= 1.1f) return x;
  if (x <= -1.1f) return 0.f;
  float u = x + 1.1f;
  return u * u * (1.f / 4.4f);
}
DEVI v8bf ld8(const u16* p) { return *reinterpret_cast<const v8bf*>(p); }
DEVI v4f ldw(const u16* p) { return *reinterpret_cast<const v4f*>(p); }
DEVI v8bf asbf(v4f x) { return __builtin_bit_cast(v8bf, x); }
DEVI void pin(v4f& x) { asm("" : "+v"(x)); }       // launder -> long-term AGPR park
DEVI v4f mfma16(v8bf a, v8bf b, v4f c) {
  return __builtin_amdgcn_mfma_f32_16x16x32_bf16(a, b, c, 0, 0, 0);
}

// ---- prologue: convert all weight matrices f32 -> bf16 into d_ws ----
// Also builds W1F: fused padded head-W1, 16 out-cols x 256 K where
// K 0..127 = temphr activations, 128..255 = class activations.
__global__ void cvt_weights(const float* __restrict__ eWih, const float* __restrict__ eWhh,
                            const float* __restrict__ dWih, const float* __restrict__ dWhh,
                            const float* __restrict__ thW0, const float* __restrict__ thW1,
                            const float* __restrict__ clW0, const float* __restrict__ clW1,
                            u16* __restrict__ ws) {
  const int i = blockIdx.x * 256 + threadIdx.x;
  if (i >= W_TOTALF) return;
  if (i >= W_W1F) {
    const int r = i - W_W1F, c = r >> 8, k = r & 255;
    float v = 0.f;
    if (c < 2 && k < 128) v = thW1[c * 128 + k];
    else if (c >= 2 && c < FOUTC && k >= 128) v = clW1[(c - 2) * 128 + (k - 128)];
    ws[i] = f2bf(v);
    return;
  }
  const float* src; int off;
  if      (i < W_EWHH) { src = eWih; off = W_EWIH; }
  else if (i < W_DWIH) { src = eWhh; off = W_EWHH; }
  else if (i < W_DWHH) { src = dWih; off = W_DWIH; }
  else if (i < W_THW0) { src = dWhh; off = W_DWHH; }
  else if (i < W_THW1) { src = thW0; off = W_THW0; }
  else if (i < W_CLW0) { src = thW1; off = W_THW1; }
  else if (i < W_CLW1) { src = clW0; off = W_CLW0; }
  else                 { src = clW1; off = W_CLW1; }
  ws[i] = f2bf(src[i - off]);
}

// 1024 threads = 16 waves @ 4 waves/SIMD (128 regs/wave: 64 pinned AGPR
// z,n + <=64 arch working set). Wave w owns ONE gate col-tile c = w; r-gate
// streams from the full 132KB LDS slab. Round-1 retry with the identified
// spill sources removed: (a) gemm2 uses pre-padded W1F (no masked b-frag
// construction), (b) x staged via LDS (1 live reg, aliased into a1x which
// the encoder doesn't use), (c) biases folded into MFMA C-init, (d) gemm
// frames reuse the dead gate-accum registers (sequential phases).
// Latency model from r0/r3: 1 wave/SIMD = 18.7k cyc/step, 2 = 10.7k;
// 4 waves spill-free is the remaining untested config.
__global__ __launch_bounds__(1024, 4) void encdec_kernel(
    const float* __restrict__ xf, const float* __restrict__ yt, const float* __restrict__ pp,
    const float* __restrict__ ebih, const float* __restrict__ ebhh,
    const float* __restrict__ dbih, const float* __restrict__ dbhh,
    const float* __restrict__ thb0, const float* __restrict__ thb1,
    const float* __restrict__ clb0, const float* __restrict__ clb1,
    const u16* __restrict__ ws, float* __restrict__ outp) {
  __shared__ __align__(16) u16 slab[256 * SSTR];   // r-gate Whh rows (132 KB)
  __shared__ __align__(16) u16 hls[2][16 * HSTR];  // h double buffer (enc+dec)
  __shared__ __align__(16) u16 a1x[16 * HSTR];     // dec: a1; enc: x dbuf [2][16*XSTR]
  __shared__ __align__(16) u16 uls[2][16 * UST2];

  const u16* eWih = ws + W_EWIH;
  const u16* eWhh = ws + W_EWHH;
  const u16* dWih = ws + W_DWIH;
  const u16* dWhh = ws + W_DWHH;
  const u16* thW0 = ws + W_THW0;
  const u16* clW0 = ws + W_CLW0;
  const u16* w1f  = ws + W_W1F;

  const int tid = threadIdx.x;
  const int wave = tid >> 6;        // 16 waves
  const int lane = tid & 63;
  const int col16 = lane & 15;
  const int quad = lane >> 4;
  const int n0 = blockIdx.x * 16;

  const int cidx = wave * 16 + col16;          // owned gate/output column
  const int mz = 256 + cidx, mn = 512 + cidx;

  float hreg[4] = {0.f, 0.f, 0.f, 0.f};

  // Persistent z,n Whh fragments (64 regs -> AGPR park).
  v4f wz[8], wn[8];
  float bsr, bsz, bin_, bhn;

  const u16* sp = slab + cidx * SSTR + quad * 8;
  // x staging: thread (wave=row, lane=col) covers the 16x64 step slice
  const float* xsrc = xf + ((size_t)(n0 + wave) * LX) * FF + lane;

  // ================= encoder phase =================
  {
    for (int i = tid; i < 256 * 32; i += 1024) {  // stage r-gate Whh slab
      const int row = i >> 5, kb = (i & 31) << 3;
      *reinterpret_cast<v8bf*>(&slab[row * SSTR + kb]) = ld8(eWhh + row * HID + kb);
    }
    for (int i = tid; i < 16 * HSTR; i += 1024) hls[0][i] = 0;
    a1x[wave * XSTR + lane] = f2bf(xsrc[0]);      // stage x(0) into x-buf 0
#pragma unroll
    for (int k = 0; k < 8; ++k) {
      wz[k] = ldw(eWhh + (size_t)mz * HID + k * 32 + quad * 8); pin(wz[k]);
      wn[k] = ldw(eWhh + (size_t)mn * HID + k * 32 + quad * 8); pin(wn[k]);
    }
    bsr = ebih[cidx] + ebhh[cidx];
    bsz = ebih[mz] + ebhh[mz];
    bin_ = ebih[mn];
    bhn = ebhh[mn];

    const u16* pwr = eWih + (size_t)cidx * FF + quad * 8;
    const u16* pwz = eWih + (size_t)mz * FF + quad * 8;
    const u16* pwn = eWih + (size_t)mn * FF + quad * 8;
    __syncthreads();  // slab + h-init + x(0) visible

#pragma unroll 1
    for (int t = 0; t < LX; ++t) {
      float xn = 0.f;
      if (t + 1 < LX) xn = xsrc[(size_t)(t + 1) * FF];  // issue early, use late

      const u16* hb = hls[t & 1] + col16 * HSTR + quad * 8;
      v4f az = {bsz, bsz, bsz, bsz};
      v4f ar = {bsr, bsr, bsr, bsr};
      v4f an = {bhn, bhn, bhn, bhn};
      v4f ai = {bin_, bin_, bin_, bin_};
      __builtin_amdgcn_s_setprio(1);
#pragma unroll
      for (int k = 0; k < 8; ++k) {            // on-the-fly h fragments
        const v8bf a = ld8(hb + k * 32);
        az = mfma16(a, asbf(wz[k]), az);
        ar = mfma16(a, ld8(sp + k * 32), ar);
        an = mfma16(a, asbf(wn[k]), an);
      }
      const u16* xb = a1x + (t & 1) * (16 * XSTR) + col16 * XSTR + quad * 8;
      const v8bf xa0 = ld8(xb);
      const v8bf xa1 = ld8(xb + 32);
      az = mfma16(xa0, ld8(pwz), az);
      az = mfma16(xa1, ld8(pwz + 32), az);
      ar = mfma16(xa0, ld8(pwr), ar);
      ar = mfma16(xa1, ld8(pwr + 32), ar);
      ai = mfma16(xa0, ld8(pwn), ai);
      ai = mfma16(xa1, ld8(pwn + 32), ai);
      __builtin_amdgcn_s_setprio(0);
#pragma unroll
      for (int r = 0; r < 4; ++r) {
        const float zg = sigm(az[r]);
        const float rg = sigm(ar[r]);
        const float ng = tanh_(ai[r] + rg * an[r]);
        hreg[r] = (1.f - zg) * ng + zg * hreg[r];
        hls[(t + 1) & 1][(quad * 4 + r) * HSTR + cidx] = f2bf(hreg[r]);
      }
      if (t + 1 < LX)
        a1x[((t + 1) & 1) * (16 * XSTR) + wave * XSTR + lane] = f2bf(xn);
      __syncthreads();
    }
  }
  // h_enc = H(168) in hls[0]  (LX even)

  // ================= decoder phase =================
  {
    for (int i = tid; i < 256 * 32; i += 1024) {  // restage slab with dWhh r rows
      const int row = i >> 5, kb = (i & 31) << 3;
      *reinterpret_cast<v8bf*>(&slab[row * SSTR + kb]) = ld8(dWhh + row * HID + kb);
    }
#pragma unroll
    for (int k = 0; k < 8; ++k) {
      wz[k] = ldw(dWhh + (size_t)mz * HID + k * 32 + quad * 8); pin(wz[k]);
      wn[k] = ldw(dWhh + (size_t)mn * HID + k * 32 + quad * 8); pin(wn[k]);
    }
    bsr = dbih[cidx] + dbhh[cidx];
    bsz = dbih[mz] + dbhh[mz];
    bin_ = dbih[mn];
    bhn = dbhh[mn];

    const bool isTh = (wave < 8);
    const int wrow = (wave & 7) * 16 + col16;        // head W0 row
    const u16* pW0 = (isTh ? thW0 : clW0) + (size_t)wrow * HID + quad * 8;
    const float hb0 = isTh ? thb0[wrow] : clb0[wrow];
    const int hcol = (isTh ? 0 : 128) + wrow;        // a1 column this wave writes

    const float b1v = (col16 < 2) ? thb1[col16]
                    : (col16 < FOUTC) ? clb1[col16 - 2] : 0.f;

    const u16* pur = dWih + (size_t)cidx * 32 + quad * 8;
    const u16* puz = dWih + (size_t)mz * 32 + quad * 8;
    const u16* pun = dWih + (size_t)mn * 32 + quad * 8;

    const int srr = tid >> 5, scc = tid & 31;        // u staging (tid < 512)
    const size_t ybase = (size_t)(n0 + srr) * (LY + 1);
    if (tid < 512) {
      const float v = (scc < FT) ? yt[ybase * FT + scc] : pp[ybase * FOUTC + (scc - FT)];
      uls[0][srr * UST2 + scc] = f2bf(v);
    }

    // GEMM2 for step s: out(s) = a1(s) @ W1F^T + b1 (plain 8-chain, W1F padded).
    auto gemm2 = [&](int s) {
      const u16* arow = a1x + col16 * HSTR + quad * 8;
      const u16* w1p = w1f + col16 * HID + quad * 8;
      v4f acc = {b1v, b1v, b1v, b1v};
#pragma unroll
      for (int kt = 0; kt < 8; ++kt)
        acc = mfma16(ld8(arow + kt * 32), ld8(w1p + kt * 32), acc);
      if (col16 < FOUTC) {
#pragma unroll
        for (int r = 0; r < 4; ++r)
          outp[((size_t)(n0 + quad * 4 + r) * LY + s) * FOUTC + col16] = acc[r];
      }
    };

    // GEMM1: a1 = smelu(H @ W0^T + b0); each wave computes its head tile.
    auto gemm1 = [&](const u16* hbase) {
      const u16* hA = hbase + col16 * HSTR + quad * 8;
      v4f acc = {hb0, hb0, hb0, hb0};
#pragma unroll
      for (int k = 0; k < 8; ++k)
        acc = mfma16(ld8(hA + k * 32), ld8(pW0 + k * 32), acc);
#pragma unroll
      for (int r = 0; r < 4; ++r)
        a1x[(quad * 4 + r) * HSTR + hcol] = f2bf(smelu_(acc[r]));
    };

    __syncthreads();  // slab + u_0 visible (last enc h write fenced by enc barrier)

#pragma unroll 1
    for (int t = 0; t < LY; ++t) {
      float un = 0.f;
      if (tid < 512 && t + 1 < LY)
        un = (scc < FT) ? yt[(ybase + t) * FT + scc]
                        : pp[(ybase + t) * FOUTC + (scc - FT)];

      // ---- phase A: gemm2(t-2) reads a1x (written step t-1 phase B) ----
      if (wave == 0 && t >= 2) gemm2(t - 2);

      const v8bf ua = ld8(uls[t & 1] + col16 * UST2 + quad * 8);
      const u16* hb = hls[t & 1] + col16 * HSTR + quad * 8;
      v4f az = {bsz, bsz, bsz, bsz};
      v4f ar = {bsr, bsr, bsr, bsr};
      v4f an = {bhn, bhn, bhn, bhn};
      v4f ai = {bin_, bin_, bin_, bin_};
      __builtin_amdgcn_s_setprio(1);
#pragma unroll
      for (int k = 0; k < 8; ++k) {
        const v8bf a = ld8(hb + k * 32);
        az = mfma16(a, asbf(wz[k]), az);
        ar = mfma16(a, ld8(sp + k * 32), ar);
        an = mfma16(a, asbf(wn[k]), an);
      }
      az = mfma16(ua, ld8(puz), az);
      ar = mfma16(ua, ld8(pur), ar);
      ai = mfma16(ua, ld8(pun), ai);
      __builtin_amdgcn_s_setprio(0);
#pragma unroll
      for (int r = 0; r < 4; ++r) {
        const float zg = sigm(az[r]);
        const float rg = sigm(ar[r]);
        const float ng = tanh_(ai[r] + rg * an[r]);
        hreg[r] = (1.f - zg) * ng + zg * hreg[r];
        hls[(t + 1) & 1][(quad * 4 + r) * HSTR + cidx] = f2bf(hreg[r]);
      }
      if (tid < 512 && t + 1 < LY) uls[(t + 1) & 1][srr * UST2 + scc] = f2bf(un);
      __syncthreads();  // bar1: gemm2's a1x reads done; H(t+1)/u(t+1) visible

      // ---- phase B: gemm1(t-1) reads hls[t&1] (= H(t)), writes a1x ----
      if (t >= 1) gemm1(hls[t & 1]);
      __syncthreads();  // bar2: a1x(t-1) visible for next step's gemm2
    }

    // ---- epilogue: a1x holds a1(LY-2) ----
    if (wave == 0) gemm2(LY - 2);
    __syncthreads();
    gemm1(hls[LY & 1]);              // a1(LY-1) from H(LY) (= hls[0], LY even)
    __syncthreads();
    if (wave == 0) gemm2(LY - 1);
  }
}

extern "C" void kernel_launch(void* const* d_in, const int* in_sizes, int n_in,
                              void* d_out, int out_size, void* d_ws, size_t ws_size,
                              hipStream_t stream) {
  (void)in_sizes; (void)n_in; (void)ws_size; (void)out_size;
  const float* xf   = (const float*)d_in[0];
  // d_in[1] = x : unused by forward
  const float* yt   = (const float*)d_in[2];
  const float* pp   = (const float*)d_in[3];
  const float* eWih = (const float*)d_in[4];
  const float* eWhh = (const float*)d_in[5];
  const float* ebih = (const float*)d_in[6];
  const float* ebhh = (const float*)d_in[7];
  const float* dWih = (const float*)d_in[8];
  const float* dWhh = (const float*)d_in[9];
  const float* dbih = (const float*)d_in[10];
  const float* dbhh = (const float*)d_in[11];
  const float* thW0 = (const float*)d_in[12];
  const float* thb0 = (const float*)d_in[13];
  const float* thW1 = (const float*)d_in[14];
  const float* thb1 = (const float*)d_in[15];
  const float* clW0 = (const float*)d_in[16];
  const float* clb0 = (const float*)d_in[17];
  const float* clW1 = (const float*)d_in[18];
  const float* clb1 = (const float*)d_in[19];
  float* outp = (float*)d_out;
  u16* ws = (u16*)d_ws;  // needs W_TOTALF*2 ~= 1.05 MB of scratch

  cvt_weights<<<dim3((W_TOTALF + 255) / 256), dim3(256), 0, stream>>>(
      eWih, eWhh, dWih, dWhh, thW0, thW1, clW0, clW1, ws);
  encdec_kernel<<<dim3(128), dim3(1024), 0, stream>>>(
      xf, yt, pp, ebih, ebhh, dbih, dbhh, thb0, thb1, clb0, clb1, ws, outp);
}